// Round 1
// baseline (197.253 us; speedup 1.0000x reference)
//
#include <hip/hip_runtime.h>
#include <math.h>

#define LOG2E 1.44269504088896340736f
#define LN2   0.69314718055994530942f

typedef _Float16 half8 __attribute__((ext_vector_type(8)));
typedef float f32x4v __attribute__((ext_vector_type(4)));

#define AROW 24   // halves per LDS row (48B): 16B-aligned frag reads

// ---------------------------------------------------------------------------
// kA: Lout[fb][b][g] = sum_{f in 1024-range} exp( dot16(A[:,f], T[:,g]) )
// via mfma_f32_16x16x32_f16 with [Ah|Al] x [Th|Th] + [Ah|Al] x [Tl|0].
// grid (16 gb, 2 fb, 32 b), block 256 (4 waves; wave owns 32 g-columns).
// 1024 blocks = exactly 4 blocks/CU (16 waves/CU at VGPR<=128).
// Pipeline: double-buffered LDS; next chunk's global loads issue BEFORE the
// current chunk's MFMA+exp; cvt+LDS-write after; ONE barrier per chunk.
// ---------------------------------------------------------------------------
template <bool ATOMIC>
__global__ __launch_bounds__(256, 4) void kA(const float* __restrict__ data,
                                             const float* __restrict__ attn,
                                             float* __restrict__ Lout) {
    __shared__ _Float16 AhB[2][128 * AROW];
    __shared__ _Float16 AlB[2][128 * AROW];
    const int tid = threadIdx.x;
    const int b = blockIdx.z, fb = blockIdx.y, gb = blockIdx.x;
    const int wave = tid >> 6, lane = tid & 63;
    const int n = lane & 15, q = lane >> 4;
    const int s0 = (q & 1) * 8;

    // B fragments (loop-invariant). B[k=q*8+j][n]; k mod 16 = s0+j.
    const float* Tb = attn + (size_t)b * 16 * 2048;
    half8 B1[2], B2[2];
#pragma unroll
    for (int ct = 0; ct < 2; ++ct) {
        const int g = gb * 128 + wave * 32 + ct * 16 + n;
        half8 bh, bl;
#pragma unroll
        for (int j = 0; j < 8; ++j) {
            float x = Tb[(size_t)(s0 + j) * 2048 + g] * LOG2E;
            _Float16 h = (_Float16)x;
            _Float16 l = (_Float16)(x - (float)h);
            bh[j] = h;
            bl[j] = (q < 2) ? l : (_Float16)0.0f;
        }
        B1[ct] = bh;
        B2[ct] = bl;
    }

    f32x4v cs0 = {0.f, 0.f, 0.f, 0.f}, cs1 = {0.f, 0.f, 0.f, 0.f};

    const float* Ab = data + (size_t)b * 16 * 2048 + fb * 1024;
    const int fst = tid & 127;       // f-row within tile (wave-consecutive)
    const int sh  = (tid >> 7) * 8;  // s-half

    // prologue: stage chunk 0 into buffer 0
    {
        float x[8];
#pragma unroll
        for (int j = 0; j < 8; ++j) x[j] = Ab[(size_t)(sh + j) * 2048 + fst];
        half8 hv, lv;
#pragma unroll
        for (int j = 0; j < 8; ++j) {
            _Float16 h = (_Float16)x[j];
            hv[j] = h;
            lv[j] = (_Float16)(x[j] - (float)h);
        }
        *(half8*)(&AhB[0][fst * AROW + sh]) = hv;
        *(half8*)(&AlB[0][fst * AROW + sh]) = lv;
    }
    __syncthreads();

#pragma unroll 2
    for (int c = 0; c < 8; ++c) {
        const int cur = c & 1;
        // issue next chunk's global loads first — they fly under the MFMA+exp
        float xn[8];
        if (c < 7) {
            const float* Ac = Ab + (c + 1) * 128;
#pragma unroll
            for (int j = 0; j < 8; ++j) xn[j] = Ac[(size_t)(sh + j) * 2048 + fst];
        }

        const _Float16* aptr = ((q < 2) ? AhB[cur] : AlB[cur]) + n * AROW + s0;
#pragma unroll
        for (int rt = 0; rt < 8; ++rt) {
            half8 af = *(const half8*)(aptr + rt * 16 * AROW);
            f32x4v C = {0.f, 0.f, 0.f, 0.f};
            C = __builtin_amdgcn_mfma_f32_16x16x32_f16(af, B1[0], C, 0, 0, 0);
            C = __builtin_amdgcn_mfma_f32_16x16x32_f16(af, B2[0], C, 0, 0, 0);
            cs0[0] += __builtin_amdgcn_exp2f(C[0]);
            cs0[1] += __builtin_amdgcn_exp2f(C[1]);
            cs0[2] += __builtin_amdgcn_exp2f(C[2]);
            cs0[3] += __builtin_amdgcn_exp2f(C[3]);
            f32x4v D = {0.f, 0.f, 0.f, 0.f};
            D = __builtin_amdgcn_mfma_f32_16x16x32_f16(af, B1[1], D, 0, 0, 0);
            D = __builtin_amdgcn_mfma_f32_16x16x32_f16(af, B2[1], D, 0, 0, 0);
            cs1[0] += __builtin_amdgcn_exp2f(D[0]);
            cs1[1] += __builtin_amdgcn_exp2f(D[1]);
            cs1[2] += __builtin_amdgcn_exp2f(D[2]);
            cs1[3] += __builtin_amdgcn_exp2f(D[3]);
        }

        if (c < 7) {
            // convert and stage into the other buffer; one barrier per chunk.
            half8 hv, lv;
#pragma unroll
            for (int j = 0; j < 8; ++j) {
                _Float16 h = (_Float16)xn[j];
                hv[j] = h;
                lv[j] = (_Float16)(xn[j] - (float)h);
            }
            const int nxt = cur ^ 1;
            *(half8*)(&AhB[nxt][fst * AROW + sh]) = hv;
            *(half8*)(&AlB[nxt][fst * AROW + sh]) = lv;
            __syncthreads();
        }
    }

    float v0 = cs0[0] + cs0[1] + cs0[2] + cs0[3];
    float v1 = cs1[0] + cs1[1] + cs1[2] + cs1[3];
    v0 += __shfl_xor(v0, 16);
    v0 += __shfl_xor(v0, 32);
    v1 += __shfl_xor(v1, 16);
    v1 += __shfl_xor(v1, 32);
    if (q == 0) {
        const int g = gb * 128 + wave * 32 + n;
        if (ATOMIC) {
            atomicAdd(&Lout[(size_t)b * 2048 + g], v0);
            atomicAdd(&Lout[(size_t)b * 2048 + g + 16], v1);
        } else {
            Lout[((size_t)fb * 32 + b) * 2048 + g] = v0;
            Lout[((size_t)fb * 32 + b) * 2048 + g + 16] = v1;
        }
    }
}

// ---------------------------------------------------------------------------
// kTail: per (256-g segment, b): L = ln2*log2(sum Lpart), c-partials, M-partials.
// grid (8, 32), block 256.
// ---------------------------------------------------------------------------
#define TP 260
__global__ __launch_bounds__(256) void kTail(const float* __restrict__ attn,
                                             const float* __restrict__ Lpart, int nparts,
                                             float* __restrict__ Mpart,
                                             float* __restrict__ cpart) {
    __shared__ float Tsh[16 * TP];   // 16.6 KB
    __shared__ float Lsh[256];
    __shared__ float red[16][17];
    const int tid = threadIdx.x;
    const int seg = blockIdx.x, b = blockIdx.y;
    const int g0 = seg * 256;

#pragma unroll
    for (int s = 0; s < 16; ++s)
        Tsh[s * TP + tid] = attn[(size_t)(b * 16 + s) * 2048 + g0 + tid];
    {
        float sum = 0.f;
        for (int p = 0; p < nparts; ++p)
            sum += Lpart[((size_t)p * 32 + b) * 2048 + g0 + tid];
        Lsh[tid] = LN2 * __builtin_amdgcn_logf(sum);
    }
    __syncthreads();

    // c-partial: t = tid&15 over a 16-g subrange
    {
        const int t = tid & 15, i = tid >> 4;
        float acc = 0.f;
#pragma unroll
        for (int k = 0; k < 4; ++k) {
            float4 l  = *(const float4*)(Lsh + i * 16 + k * 4);
            float4 tv = *(const float4*)(Tsh + t * TP + i * 16 + k * 4);
            acc += l.x * tv.x + l.y * tv.y + l.z * tv.z + l.w * tv.w;
        }
        red[t][i] = acc;
    }
    __syncthreads();
    if (tid < 16) {
        float s = 0.f;
#pragma unroll
        for (int k = 0; k < 16; ++k) s += red[tid][k];
        cpart[((size_t)seg * 32 + b) * 16 + tid] = s;
    }

    // M-partial: thread = (s,t)
    {
        const int s = tid >> 4, t = tid & 15;
        float a0 = 0.f, a1 = 0.f;
#pragma unroll 4
        for (int qk = 0; qk < 32; ++qk) {
            float4 x = *(const float4*)(Tsh + s * TP + qk * 8);
            float4 y = *(const float4*)(Tsh + t * TP + qk * 8);
            a0 += x.x * y.x + x.y * y.y + x.z * y.z + x.w * y.w;
            float4 x2 = *(const float4*)(Tsh + s * TP + qk * 8 + 4);
            float4 y2 = *(const float4*)(Tsh + t * TP + qk * 8 + 4);
            a1 += x2.x * y2.x + x2.y * y2.y + x2.z * y2.z + x2.w * y2.w;
        }
        Mpart[((size_t)seg * 32 + b) * 256 + tid] = a0 + a1;
    }
}

// ---------------------------------------------------------------------------
// kC2: fold M/c partials with W,bias (redundant per block, cheap) + epilogue.
// grid (8, 32), block 256.
// ---------------------------------------------------------------------------
__global__ __launch_bounds__(256) void kC2(const float* __restrict__ data,
                                           const float* __restrict__ Mpart,
                                           const float* __restrict__ cpart,
                                           const float* __restrict__ W,
                                           const float* __restrict__ bias,
                                           float* __restrict__ out) {
    __shared__ float Msh[256];
    __shared__ float csh[16];
    __shared__ float Vsh[256];
    __shared__ float w0sh[16];
    const int tid = threadIdx.x;
    const int b = blockIdx.y;
    const int f = blockIdx.x * 256 + tid;

    {
        float m = 0.f;
#pragma unroll
        for (int p = 0; p < 8; ++p) m += Mpart[((size_t)p * 32 + b) * 256 + tid];
        Msh[tid] = m;
        if (tid < 16) {
            float c = 0.f;
#pragma unroll
            for (int p = 0; p < 8; ++p) c += cpart[((size_t)p * 32 + b) * 16 + tid];
            csh[tid] = c;
        }
    }
    __syncthreads();
    {
        const int s = tid >> 4, j = tid & 15;
        float acc = 0.f;
#pragma unroll
        for (int t = 0; t < 16; ++t) acc += Msh[s * 16 + t] * W[j * 32 + t];
        Vsh[s * 16 + j] = acc + W[j * 32 + 16 + s];
        if (s == 0) {
            float w0 = 0.f;
#pragma unroll
            for (int t = 0; t < 16; ++t) w0 += csh[t] * W[j * 32 + t];
            w0sh[j] = bias[j] - w0;
        }
    }
    __syncthreads();

    float As[16];
#pragma unroll
    for (int s = 0; s < 16; ++s)
        As[s] = data[(size_t)(b * 16 + s) * 2048 + f];
#pragma unroll
    for (int j = 0; j < 16; ++j) {
        float p = w0sh[j];
#pragma unroll
        for (int s = 0; s < 16; ++s) p += As[s] * Vsh[s * 16 + j];
        float e = __builtin_amdgcn_exp2f(-LOG2E * p);
        float gate = __builtin_amdgcn_rcpf(1.0f + e);
        size_t r = (size_t)(j * 32 + b) * 2048 + f;
        out[r] = gate * data[r];
    }
}

extern "C" void kernel_launch(void* const* d_in, const int* in_sizes, int n_in,
                              void* d_out, int out_size, void* d_ws, size_t ws_size,
                              hipStream_t stream) {
    const float* data = (const float*)d_in[0];
    const float* attn = (const float*)d_in[1];
    const float* W    = (const float*)d_in[2];
    const float* bias = (const float*)d_in[3];
    float* out = (float*)d_out;
    float* ws  = (float*)d_ws;

    // big layout: Lpart[2][32][2048] | Mpart[8][32][256] | cpart[8][32][16]
    const size_t LP = 2 * 32 * 2048;              // 131072
    const size_t need_big = LP + 65536 + 4096;

    if (ws_size >= need_big * sizeof(float)) {
        float* Lpart = ws;
        float* Mpart = ws + LP;
        float* cpart = Mpart + 65536;
        kA<false><<<dim3(16, 2, 32), 256, 0, stream>>>(data, attn, Lpart);
        kTail<<<dim3(8, 32), 256, 0, stream>>>(attn, Lpart, 2, Mpart, cpart);
        kC2<<<dim3(8, 32), 256, 0, stream>>>(data, Mpart, cpart, W, bias, out);
    } else {
        float* Lsum  = ws;            // 65536
        float* Mpart = ws + 65536;
        float* cpart = Mpart + 65536;
        hipMemsetAsync(Lsum, 0, 65536 * sizeof(float), stream);
        kA<true><<<dim3(16, 2, 32), 256, 0, stream>>>(data, attn, Lsum);
        kTail<<<dim3(8, 32), 256, 0, stream>>>(attn, Lsum, 1, Mpart, cpart);
        kC2<<<dim3(8, 32), 256, 0, stream>>>(data, Mpart, cpart, W, bias, out);
    }
}

// Round 2
// 94.459 us; speedup vs baseline: 2.0882x; 2.0882x over previous
//
#include <hip/hip_runtime.h>
#include <math.h>

#define LOG2E 1.44269504088896340736f
#define LN2   0.69314718055994530942f

typedef _Float16 half8 __attribute__((ext_vector_type(8)));
typedef float f32x4v __attribute__((ext_vector_type(4)));

#define AROW 24   // halves per LDS row (48B): 16B-aligned frag reads

// ---------------------------------------------------------------------------
// kA: Lout[fb][b][g] = sum_{f in 512-range} exp( dot16(A[:,f], T[:,g]) )
// via mfma_f32_16x16x32_f16 with [Ah|Al] x [Th|Th] + [Ah|Al] x [Tl|0].
// grid linear 2048 blocks, decode b=x&31, fb=(x>>5)&3, gb=x>>7 so that all
// blocks sharing a (fb,b) data slice / a b attn slice have ids ≡ (mod 8)
// -> same XCD under round-robin dispatch -> per-XCD L2 holds its 1MB set.
// block 256 (4 waves; wave owns 32 g-columns). 8 blocks/CU, VGPR<=64.
// ---------------------------------------------------------------------------
template <bool ATOMIC>
__global__ __launch_bounds__(256, 4) void kA(const float* __restrict__ data,
                                             const float* __restrict__ attn,
                                             float* __restrict__ Lout) {
    __shared__ _Float16 AhB[128 * AROW];
    __shared__ _Float16 AlB[128 * AROW];
    const int tid = threadIdx.x;
    const int lin = blockIdx.x;
    const int b = lin & 31, fb = (lin >> 5) & 3, gb = lin >> 7;
    const int wave = tid >> 6, lane = tid & 63;
    const int n = lane & 15, q = lane >> 4;
    const int s0 = (q & 1) * 8;

    // B fragments (loop-invariant). B[k=q*8+j][n]; k mod 16 = s0+j.
    const float* Tb = attn + (size_t)b * 16 * 2048;
    half8 B1[2], B2[2];
#pragma unroll
    for (int ct = 0; ct < 2; ++ct) {
        const int g = gb * 128 + wave * 32 + ct * 16 + n;
        half8 bh, bl;
#pragma unroll
        for (int j = 0; j < 8; ++j) {
            float x = Tb[(size_t)(s0 + j) * 2048 + g] * LOG2E;
            _Float16 h = (_Float16)x;
            _Float16 l = (_Float16)(x - (float)h);
            bh[j] = h;
            bl[j] = (q < 2) ? l : (_Float16)0.0f;
        }
        B1[ct] = bh;
        B2[ct] = bl;
    }

    f32x4v cs0 = {0.f, 0.f, 0.f, 0.f}, cs1 = {0.f, 0.f, 0.f, 0.f};

    const float* Ab = data + (size_t)b * 16 * 2048 + fb * 512;
    const int fst = tid & 127;       // f-row within tile (wave-consecutive)
    const int sh  = (tid >> 7) * 8;  // s-half
    const _Float16* aptr = ((q < 2) ? AhB : AlB) + n * AROW + s0;

    for (int chunk = 0; chunk < 4; ++chunk) {
        const float* Ac = Ab + chunk * 128;
        _Float16 hb[8], lb[8];
#pragma unroll
        for (int j = 0; j < 8; ++j) {
            float x = Ac[(size_t)(sh + j) * 2048 + fst];
            _Float16 h = (_Float16)x;
            hb[j] = h;
            lb[j] = (_Float16)(x - (float)h);
        }
        __syncthreads();  // previous chunk's compute done
        half8 hv, lv;
#pragma unroll
        for (int j = 0; j < 8; ++j) { hv[j] = hb[j]; lv[j] = lb[j]; }
        *(half8*)(AhB + fst * AROW + sh) = hv;
        *(half8*)(AlB + fst * AROW + sh) = lv;
        __syncthreads();

#pragma unroll
        for (int rt = 0; rt < 8; ++rt) {
            half8 af = *(const half8*)(aptr + rt * 16 * AROW);
            f32x4v C = {0.f, 0.f, 0.f, 0.f};
            C = __builtin_amdgcn_mfma_f32_16x16x32_f16(af, B1[0], C, 0, 0, 0);
            C = __builtin_amdgcn_mfma_f32_16x16x32_f16(af, B2[0], C, 0, 0, 0);
            cs0[0] += __builtin_amdgcn_exp2f(C[0]);
            cs0[1] += __builtin_amdgcn_exp2f(C[1]);
            cs0[2] += __builtin_amdgcn_exp2f(C[2]);
            cs0[3] += __builtin_amdgcn_exp2f(C[3]);
            f32x4v D = {0.f, 0.f, 0.f, 0.f};
            D = __builtin_amdgcn_mfma_f32_16x16x32_f16(af, B1[1], D, 0, 0, 0);
            D = __builtin_amdgcn_mfma_f32_16x16x32_f16(af, B2[1], D, 0, 0, 0);
            cs1[0] += __builtin_amdgcn_exp2f(D[0]);
            cs1[1] += __builtin_amdgcn_exp2f(D[1]);
            cs1[2] += __builtin_amdgcn_exp2f(D[2]);
            cs1[3] += __builtin_amdgcn_exp2f(D[3]);
        }
    }

    float v0 = cs0[0] + cs0[1] + cs0[2] + cs0[3];
    float v1 = cs1[0] + cs1[1] + cs1[2] + cs1[3];
    v0 += __shfl_xor(v0, 16);
    v0 += __shfl_xor(v0, 32);
    v1 += __shfl_xor(v1, 16);
    v1 += __shfl_xor(v1, 32);
    if (q == 0) {
        const int g = gb * 128 + wave * 32 + n;
        if (ATOMIC) {
            atomicAdd(&Lout[(size_t)b * 2048 + g], v0);
            atomicAdd(&Lout[(size_t)b * 2048 + g + 16], v1);
        } else {
            Lout[((size_t)fb * 32 + b) * 2048 + g] = v0;
            Lout[((size_t)fb * 32 + b) * 2048 + g + 16] = v1;
        }
    }
}

// ---------------------------------------------------------------------------
// kTail: per (256-g segment, b): L = ln2*log2(sum Lpart), c-partials, M-partials.
// grid (8, 32), block 256.
// ---------------------------------------------------------------------------
#define TP 260
__global__ __launch_bounds__(256) void kTail(const float* __restrict__ attn,
                                             const float* __restrict__ Lpart, int nparts,
                                             float* __restrict__ Mpart,
                                             float* __restrict__ cpart) {
    __shared__ float Tsh[16 * TP];   // 16.6 KB
    __shared__ float Lsh[256];
    __shared__ float red[16][17];
    const int tid = threadIdx.x;
    const int seg = blockIdx.x, b = blockIdx.y;
    const int g0 = seg * 256;

#pragma unroll
    for (int s = 0; s < 16; ++s)
        Tsh[s * TP + tid] = attn[(size_t)(b * 16 + s) * 2048 + g0 + tid];
    {
        float sum = 0.f;
        for (int p = 0; p < nparts; ++p)
            sum += Lpart[((size_t)p * 32 + b) * 2048 + g0 + tid];
        Lsh[tid] = LN2 * __builtin_amdgcn_logf(sum);
    }
    __syncthreads();

    // c-partial: t = tid&15 over a 16-g subrange
    {
        const int t = tid & 15, i = tid >> 4;
        float acc = 0.f;
#pragma unroll
        for (int k = 0; k < 4; ++k) {
            float4 l  = *(const float4*)(Lsh + i * 16 + k * 4);
            float4 tv = *(const float4*)(Tsh + t * TP + i * 16 + k * 4);
            acc += l.x * tv.x + l.y * tv.y + l.z * tv.z + l.w * tv.w;
        }
        red[t][i] = acc;
    }
    __syncthreads();
    if (tid < 16) {
        float s = 0.f;
#pragma unroll
        for (int k = 0; k < 16; ++k) s += red[tid][k];
        cpart[((size_t)seg * 32 + b) * 16 + tid] = s;
    }

    // M-partial: thread = (s,t)
    {
        const int s = tid >> 4, t = tid & 15;
        float a0 = 0.f, a1 = 0.f;
#pragma unroll 4
        for (int qk = 0; qk < 32; ++qk) {
            float4 x = *(const float4*)(Tsh + s * TP + qk * 8);
            float4 y = *(const float4*)(Tsh + t * TP + qk * 8);
            a0 += x.x * y.x + x.y * y.y + x.z * y.z + x.w * y.w;
            float4 x2 = *(const float4*)(Tsh + s * TP + qk * 8 + 4);
            float4 y2 = *(const float4*)(Tsh + t * TP + qk * 8 + 4);
            a1 += x2.x * y2.x + x2.y * y2.y + x2.z * y2.z + x2.w * y2.w;
        }
        Mpart[((size_t)seg * 32 + b) * 256 + tid] = a0 + a1;
    }
}

// ---------------------------------------------------------------------------
// kC2: fold M/c partials with W,bias (redundant per block, cheap) + epilogue.
// grid (8, 32), block 256.
// ---------------------------------------------------------------------------
__global__ __launch_bounds__(256) void kC2(const float* __restrict__ data,
                                           const float* __restrict__ Mpart,
                                           const float* __restrict__ cpart,
                                           const float* __restrict__ W,
                                           const float* __restrict__ bias,
                                           float* __restrict__ out) {
    __shared__ float Msh[256];
    __shared__ float csh[16];
    __shared__ float Vsh[256];
    __shared__ float w0sh[16];
    const int tid = threadIdx.x;
    const int b = blockIdx.y;
    const int f = blockIdx.x * 256 + tid;

    {
        float m = 0.f;
#pragma unroll
        for (int p = 0; p < 8; ++p) m += Mpart[((size_t)p * 32 + b) * 256 + tid];
        Msh[tid] = m;
        if (tid < 16) {
            float c = 0.f;
#pragma unroll
            for (int p = 0; p < 8; ++p) c += cpart[((size_t)p * 32 + b) * 16 + tid];
            csh[tid] = c;
        }
    }
    __syncthreads();
    {
        const int s = tid >> 4, j = tid & 15;
        float acc = 0.f;
#pragma unroll
        for (int t = 0; t < 16; ++t) acc += Msh[s * 16 + t] * W[j * 32 + t];
        Vsh[s * 16 + j] = acc + W[j * 32 + 16 + s];
        if (s == 0) {
            float w0 = 0.f;
#pragma unroll
            for (int t = 0; t < 16; ++t) w0 += csh[t] * W[j * 32 + t];
            w0sh[j] = bias[j] - w0;
        }
    }
    __syncthreads();

    float As[16];
#pragma unroll
    for (int s = 0; s < 16; ++s)
        As[s] = data[(size_t)(b * 16 + s) * 2048 + f];
#pragma unroll
    for (int j = 0; j < 16; ++j) {
        float p = w0sh[j];
#pragma unroll
        for (int s = 0; s < 16; ++s) p += As[s] * Vsh[s * 16 + j];
        float e = __builtin_amdgcn_exp2f(-LOG2E * p);
        float gate = __builtin_amdgcn_rcpf(1.0f + e);
        size_t r = (size_t)(j * 32 + b) * 2048 + f;
        out[r] = gate * data[r];
    }
}

extern "C" void kernel_launch(void* const* d_in, const int* in_sizes, int n_in,
                              void* d_out, int out_size, void* d_ws, size_t ws_size,
                              hipStream_t stream) {
    const float* data = (const float*)d_in[0];
    const float* attn = (const float*)d_in[1];
    const float* W    = (const float*)d_in[2];
    const float* bias = (const float*)d_in[3];
    float* out = (float*)d_out;
    float* ws  = (float*)d_ws;

    // big layout: Lpart[4][32][2048] | Mpart[8][32][256] | cpart[8][32][16]
    const size_t LP = 4 * 32 * 2048;              // 262144
    const size_t need_big = LP + 65536 + 4096;

    if (ws_size >= need_big * sizeof(float)) {
        float* Lpart = ws;
        float* Mpart = ws + LP;
        float* cpart = Mpart + 65536;
        kA<false><<<dim3(2048, 1, 1), 256, 0, stream>>>(data, attn, Lpart);
        kTail<<<dim3(8, 32), 256, 0, stream>>>(attn, Lpart, 4, Mpart, cpart);
        kC2<<<dim3(8, 32), 256, 0, stream>>>(data, Mpart, cpart, W, bias, out);
    } else {
        float* Lsum  = ws;            // 65536
        float* Mpart = ws + 65536;
        float* cpart = Mpart + 65536;
        hipMemsetAsync(Lsum, 0, 65536 * sizeof(float), stream);
        kA<true><<<dim3(2048, 1, 1), 256, 0, stream>>>(data, attn, Lsum);
        kTail<<<dim3(8, 32), 256, 0, stream>>>(attn, Lsum, 1, Mpart, cpart);
        kC2<<<dim3(8, 32), 256, 0, stream>>>(data, Mpart, cpart, W, bias, out);
    }
}

// Round 3
// 94.087 us; speedup vs baseline: 2.0965x; 1.0040x over previous
//
#include <hip/hip_runtime.h>
#include <math.h>

#define LOG2E 1.44269504088896340736f
#define LN2   0.69314718055994530942f

typedef _Float16 half8 __attribute__((ext_vector_type(8)));
typedef float f32x4v __attribute__((ext_vector_type(4)));

#define AROW 24   // halves per LDS row (48B): 16B-aligned frag reads

// ---------------------------------------------------------------------------
// kA: Lout[fb][b][g] = sum_{f in 512-range} exp( dot16(A[:,f], T[:,g]) )
// via mfma_f32_16x16x32_f16 with [Ah|Al] x [Th|Th] + [Ah|Al] x [Tl|0].
// grid linear 2048 blocks, decode b=x&31, fb=(x>>5)&3, gb=x>>7.
// block 256 (4 waves; wave owns 32 g-columns). 8 blocks/CU, VGPR<=64,
// LDS 12KB -> full 32 waves/CU residency (r0 geometry, proven 45us-class).
// Delta vs r0: next chunk's global loads are ISSUED after the second barrier,
// before the MFMA+exp compute, so ~600-900cyc of first-use latency hides
// under ~740cyc of compute instead of sitting on the critical path.
// (r1 evidence: this prefetch fits the 64-VGPR budget.)
// ---------------------------------------------------------------------------
template <bool ATOMIC>
__global__ __launch_bounds__(256, 4) void kA(const float* __restrict__ data,
                                             const float* __restrict__ attn,
                                             float* __restrict__ Lout) {
    __shared__ _Float16 AhB[128 * AROW];
    __shared__ _Float16 AlB[128 * AROW];
    const int tid = threadIdx.x;
    const int lin = blockIdx.x;
    const int b = lin & 31, fb = (lin >> 5) & 3, gb = lin >> 7;
    const int wave = tid >> 6, lane = tid & 63;
    const int n = lane & 15, q = lane >> 4;
    const int s0 = (q & 1) * 8;

    // B fragments (loop-invariant). B[k=q*8+j][n]; k mod 16 = s0+j.
    const float* Tb = attn + (size_t)b * 16 * 2048;
    half8 B1[2], B2[2];
#pragma unroll
    for (int ct = 0; ct < 2; ++ct) {
        const int g = gb * 128 + wave * 32 + ct * 16 + n;
        half8 bh, bl;
#pragma unroll
        for (int j = 0; j < 8; ++j) {
            float x = Tb[(size_t)(s0 + j) * 2048 + g] * LOG2E;
            _Float16 h = (_Float16)x;
            _Float16 l = (_Float16)(x - (float)h);
            bh[j] = h;
            bl[j] = (q < 2) ? l : (_Float16)0.0f;
        }
        B1[ct] = bh;
        B2[ct] = bl;
    }

    f32x4v cs0 = {0.f, 0.f, 0.f, 0.f}, cs1 = {0.f, 0.f, 0.f, 0.f};

    const float* Ab = data + (size_t)b * 16 * 2048 + fb * 512;
    const int fst = tid & 127;       // f-row within tile (wave-consecutive)
    const int sh  = (tid >> 7) * 8;  // s-half
    const _Float16* aptr = ((q < 2) ? AhB : AlB) + n * AROW + s0;

    // prologue: issue chunk 0's loads
    float x[8];
#pragma unroll
    for (int j = 0; j < 8; ++j) x[j] = Ab[(size_t)(sh + j) * 2048 + fst];

    for (int chunk = 0; chunk < 4; ++chunk) {
        // convert staged chunk (loads were issued one compute-phase ago)
        half8 hv, lv;
#pragma unroll
        for (int j = 0; j < 8; ++j) {
            float v = x[j];
            _Float16 h = (_Float16)v;
            hv[j] = h;
            lv[j] = (_Float16)(v - (float)h);
        }
        __syncthreads();  // previous chunk's compute done reading LDS
        *(half8*)(AhB + fst * AROW + sh) = hv;
        *(half8*)(AlB + fst * AROW + sh) = lv;
        __syncthreads();

        // issue next chunk's loads; they fly under the MFMA+exp below
        if (chunk < 3) {
            const float* Ac = Ab + (chunk + 1) * 128;
#pragma unroll
            for (int j = 0; j < 8; ++j) x[j] = Ac[(size_t)(sh + j) * 2048 + fst];
        }

#pragma unroll
        for (int rt = 0; rt < 8; ++rt) {
            half8 af = *(const half8*)(aptr + rt * 16 * AROW);
            f32x4v C = {0.f, 0.f, 0.f, 0.f};
            C = __builtin_amdgcn_mfma_f32_16x16x32_f16(af, B1[0], C, 0, 0, 0);
            C = __builtin_amdgcn_mfma_f32_16x16x32_f16(af, B2[0], C, 0, 0, 0);
            cs0[0] += __builtin_amdgcn_exp2f(C[0]);
            cs0[1] += __builtin_amdgcn_exp2f(C[1]);
            cs0[2] += __builtin_amdgcn_exp2f(C[2]);
            cs0[3] += __builtin_amdgcn_exp2f(C[3]);
            f32x4v D = {0.f, 0.f, 0.f, 0.f};
            D = __builtin_amdgcn_mfma_f32_16x16x32_f16(af, B1[1], D, 0, 0, 0);
            D = __builtin_amdgcn_mfma_f32_16x16x32_f16(af, B2[1], D, 0, 0, 0);
            cs1[0] += __builtin_amdgcn_exp2f(D[0]);
            cs1[1] += __builtin_amdgcn_exp2f(D[1]);
            cs1[2] += __builtin_amdgcn_exp2f(D[2]);
            cs1[3] += __builtin_amdgcn_exp2f(D[3]);
        }
    }

    float v0 = cs0[0] + cs0[1] + cs0[2] + cs0[3];
    float v1 = cs1[0] + cs1[1] + cs1[2] + cs1[3];
    v0 += __shfl_xor(v0, 16);
    v0 += __shfl_xor(v0, 32);
    v1 += __shfl_xor(v1, 16);
    v1 += __shfl_xor(v1, 32);
    if (q == 0) {
        const int g = gb * 128 + wave * 32 + n;
        if (ATOMIC) {
            atomicAdd(&Lout[(size_t)b * 2048 + g], v0);
            atomicAdd(&Lout[(size_t)b * 2048 + g + 16], v1);
        } else {
            Lout[((size_t)fb * 32 + b) * 2048 + g] = v0;
            Lout[((size_t)fb * 32 + b) * 2048 + g + 16] = v1;
        }
    }
}

// ---------------------------------------------------------------------------
// kTail: per (128-g segment, b): L = ln2*log2(sum Lpart), c-partials, M-partials.
// grid (16, 32) = 512 blocks -> 2 blocks/CU (was 1: pure latency exposure).
// ---------------------------------------------------------------------------
#define TP2 132
__global__ __launch_bounds__(256) void kTail(const float* __restrict__ attn,
                                             const float* __restrict__ Lpart, int nparts,
                                             float* __restrict__ Mpart,
                                             float* __restrict__ cpart) {
    __shared__ float Tsh[16 * TP2];  // 8.4 KB
    __shared__ float Lsh[128];
    __shared__ float red[16][17];
    const int tid = threadIdx.x;
    const int seg = blockIdx.x, b = blockIdx.y;
    const int g0 = seg * 128;

    {
        const int gcol = tid & 127, sh = (tid >> 7) * 8;
#pragma unroll
        for (int j = 0; j < 8; ++j) {
            const int s = sh + j;
            Tsh[s * TP2 + gcol] = attn[(size_t)(b * 16 + s) * 2048 + g0 + gcol];
        }
    }
    if (tid < 128) {
        float sum = 0.f;
        for (int p = 0; p < nparts; ++p)
            sum += Lpart[((size_t)p * 32 + b) * 2048 + g0 + tid];
        Lsh[tid] = LN2 * __builtin_amdgcn_logf(sum);
    }
    __syncthreads();

    // c-partial: c[b][t] = sum_g Lsh[g]*Tsh[t][g]; t = tid&15, i-group of 8 g
    {
        const int t = tid & 15, i = tid >> 4;
        float acc = 0.f;
#pragma unroll
        for (int k = 0; k < 2; ++k) {
            float4 l  = *(const float4*)(Lsh + i * 8 + k * 4);
            float4 tv = *(const float4*)(Tsh + t * TP2 + i * 8 + k * 4);
            acc += l.x * tv.x + l.y * tv.y + l.z * tv.z + l.w * tv.w;
        }
        red[t][i] = acc;
    }
    __syncthreads();
    if (tid < 16) {
        float s = 0.f;
#pragma unroll
        for (int k = 0; k < 16; ++k) s += red[tid][k];
        cpart[((size_t)seg * 32 + b) * 16 + tid] = s;
    }

    // M-partial: M[b][s][t] = sum_g Tsh[s][g]*Tsh[t][g]; thread = (s,t)
    {
        const int s = tid >> 4, t = tid & 15;
        float a0 = 0.f, a1 = 0.f;
#pragma unroll 4
        for (int qk = 0; qk < 16; ++qk) {
            float4 x = *(const float4*)(Tsh + s * TP2 + qk * 8);
            float4 y = *(const float4*)(Tsh + t * TP2 + qk * 8);
            a0 += x.x * y.x + x.y * y.y + x.z * y.z + x.w * y.w;
            float4 x2 = *(const float4*)(Tsh + s * TP2 + qk * 8 + 4);
            float4 y2 = *(const float4*)(Tsh + t * TP2 + qk * 8 + 4);
            a1 += x2.x * y2.x + x2.y * y2.y + x2.z * y2.z + x2.w * y2.w;
        }
        Mpart[((size_t)seg * 32 + b) * 256 + tid] = a0 + a1;
    }
}

// ---------------------------------------------------------------------------
// kC2: fold M/c partials with W,bias (redundant per block, cheap) + epilogue.
// grid (16, 32) = 512 blocks -> 2 blocks/CU; 128 f per block, 2 j-halves.
// ---------------------------------------------------------------------------
#define NSEG 16
__global__ __launch_bounds__(256) void kC2(const float* __restrict__ data,
                                           const float* __restrict__ Mpart,
                                           const float* __restrict__ cpart,
                                           const float* __restrict__ W,
                                           const float* __restrict__ bias,
                                           float* __restrict__ out) {
    __shared__ float Msh[256];
    __shared__ float csh[16];
    __shared__ float Vsh[256];
    __shared__ float w0sh[16];
    const int tid = threadIdx.x;
    const int b = blockIdx.y;
    const int f = blockIdx.x * 128 + (tid & 127);
    const int jh = tid >> 7;

    {
        float m = 0.f;
#pragma unroll
        for (int p = 0; p < NSEG; ++p) m += Mpart[((size_t)p * 32 + b) * 256 + tid];
        Msh[tid] = m;
        if (tid < 16) {
            float c = 0.f;
#pragma unroll
            for (int p = 0; p < NSEG; ++p) c += cpart[((size_t)p * 32 + b) * 16 + tid];
            csh[tid] = c;
        }
    }
    __syncthreads();
    {
        const int s = tid >> 4, j = tid & 15;
        float acc = 0.f;
#pragma unroll
        for (int t = 0; t < 16; ++t) acc += Msh[s * 16 + t] * W[j * 32 + t];
        Vsh[s * 16 + j] = acc + W[j * 32 + 16 + s];
        if (s == 0) {
            float w0 = 0.f;
#pragma unroll
            for (int t = 0; t < 16; ++t) w0 += csh[t] * W[j * 32 + t];
            w0sh[j] = bias[j] - w0;
        }
    }
    __syncthreads();

    float As[16];
#pragma unroll
    for (int s = 0; s < 16; ++s)
        As[s] = data[(size_t)(b * 16 + s) * 2048 + f];
#pragma unroll
    for (int jj = 0; jj < 8; ++jj) {
        const int j = jh * 8 + jj;
        float p = w0sh[j];
#pragma unroll
        for (int s = 0; s < 16; ++s) p += As[s] * Vsh[s * 16 + j];
        float e = __builtin_amdgcn_exp2f(-LOG2E * p);
        float gate = __builtin_amdgcn_rcpf(1.0f + e);
        size_t r = (size_t)(j * 32 + b) * 2048 + f;
        out[r] = gate * data[r];
    }
}

extern "C" void kernel_launch(void* const* d_in, const int* in_sizes, int n_in,
                              void* d_out, int out_size, void* d_ws, size_t ws_size,
                              hipStream_t stream) {
    const float* data = (const float*)d_in[0];
    const float* attn = (const float*)d_in[1];
    const float* W    = (const float*)d_in[2];
    const float* bias = (const float*)d_in[3];
    float* out = (float*)d_out;
    float* ws  = (float*)d_ws;

    // big layout: Lpart[4][32][2048] | Mpart[16][32][256] | cpart[16][32][16]
    const size_t LP = 4 * 32 * 2048;              // 262144
    const size_t MP = NSEG * 32 * 256;            // 131072
    const size_t CP = NSEG * 32 * 16;             // 8192
    const size_t need_big = LP + MP + CP;

    if (ws_size >= need_big * sizeof(float)) {
        float* Lpart = ws;
        float* Mpart = ws + LP;
        float* cpart = Mpart + MP;
        kA<false><<<dim3(2048, 1, 1), 256, 0, stream>>>(data, attn, Lpart);
        kTail<<<dim3(16, 32), 256, 0, stream>>>(attn, Lpart, 4, Mpart, cpart);
        kC2<<<dim3(16, 32), 256, 0, stream>>>(data, Mpart, cpart, W, bias, out);
    } else {
        float* Lsum  = ws;            // 65536
        float* Mpart = ws + 65536;
        float* cpart = Mpart + MP;
        hipMemsetAsync(Lsum, 0, 65536 * sizeof(float), stream);
        kA<true><<<dim3(2048, 1, 1), 256, 0, stream>>>(data, attn, Lsum);
        kTail<<<dim3(16, 32), 256, 0, stream>>>(attn, Lsum, 1, Mpart, cpart);
        kC2<<<dim3(16, 32), 256, 0, stream>>>(data, Mpart, cpart, W, bias, out);
    }
}